// Round 14
// baseline (322.322 us; speedup 1.0000x reference)
//
#include <hip/hip_runtime.h>
#include <hip/hip_fp16.h>

typedef _Float16 f16x8 __attribute__((ext_vector_type(8)));
typedef _Float16 f16x4 __attribute__((ext_vector_type(4)));
typedef float f32x4 __attribute__((ext_vector_type(4)));

#define NB 32
#define NK 64
#define ND 4
#define NH 512
#define NKP 544   // node-input K (520) padded to 17*32

// ---------------------------------------------------------------- prep ----
// Fused: obs/mask/cnt prep + u/v (layer-1 low-rank) + state-feature.

__global__ __launch_bounds__(512) void prep_fused(
    const float* __restrict__ obs, const float* __restrict__ state,
    const float* __restrict__ e1w, const float* __restrict__ e1b,
    const float* __restrict__ lw, const float* __restrict__ lb,
    float* __restrict__ maskp, float* __restrict__ cntp,
    _Float16* __restrict__ u16, _Float16* __restrict__ v16,
    _Float16* __restrict__ nodein, float* __restrict__ xfeat) {
  __shared__ __align__(16) float os[64][4];
  __shared__ float st[4];
  const int b = blockIdx.x;
  const int t = threadIdx.x;
  if (t < 4) st[t] = state[b*4 + t];
  if (t < 64) {
    float o0 = obs[(b*4 + 0)*64 + t];
    float o1 = obs[(b*4 + 1)*64 + t];
    float o2 = obs[(b*4 + 2)*64 + t];
    float o3 = obs[(b*4 + 3)*64 + t];
    os[t][0] = o0; os[t][1] = o1; os[t][2] = o2; os[t][3] = o3;
    float s = fabsf(o0) + fabsf(o1) + fabsf(o2) + fabsf(o3);
    float m = (s != 0.0f) ? 1.0f : 0.0f;
    maskp[b*64 + t] = m;
    float c = m;
    #pragma unroll
    for (int off = 1; off < 64; off <<= 1) c += __shfl_xor(c, off);
    if (t == 0) cntp[b] = fmaxf(c, 1e-6f);
    _Float16* nrow = nodein + (size_t)(b*64 + t)*NKP;
    nrow[0] = (_Float16)o0; nrow[1] = (_Float16)o1;
    nrow[2] = (_Float16)o2; nrow[3] = (_Float16)o3;
    nrow[516] = (_Float16)state[b*4 + 0];
    nrow[517] = (_Float16)state[b*4 + 1];
    nrow[518] = (_Float16)state[b*4 + 2];
    nrow[519] = (_Float16)state[b*4 + 3];
    #pragma unroll
    for (int k2 = 520; k2 < 544; ++k2) nrow[k2] = (_Float16)0.0f;
  }
  __syncthreads();
  {
    const float* wr = e1w + t*8;
    float4 wa = *(const float4*)wr;
    float4 wb = *(const float4*)(wr + 4);
    float bias = e1b[t];
    for (int j = 0; j < 64; ++j) {
      float4 ov = *(const float4*)os[j];
      float u = wa.x*ov.x + wa.y*ov.y + wa.z*ov.z + wa.w*ov.w + bias;
      float v = wb.x*ov.x + wb.y*ov.y + wb.z*ov.z + wb.w*ov.w;
      const size_t bi = (size_t)b*64 + j;
      u16[bi*NH + t] = (_Float16)u;
      v16[bi*NH + t] = (_Float16)v;
    }
  }
  {
    const float* wl = lw + t*4;
    float hv = wl[0]*st[0] + wl[1]*st[1] + wl[2]*st[2] + wl[3]*st[3] + lb[t];
    xfeat[b*1024 + t] = fmaxf(hv, 0.0f);
  }
}

__global__ void prep_w16_kernel(const float* __restrict__ e2w,
                                const float* __restrict__ e3w,
                                const float* __restrict__ n2w,
                                const float* __restrict__ n1w,
                                _Float16* __restrict__ w2h,
                                _Float16* __restrict__ w3h,
                                _Float16* __restrict__ n2wh,
                                _Float16* __restrict__ n1wh) {
  int idx = blockIdx.x * blockDim.x + threadIdx.x;
  const int A = 512*512, Bc = 512*512, C = 256*512, Dn = 512*544;
  if (idx < A) {
    w2h[idx] = (_Float16)e2w[idx];
  } else if (idx < A + Bc) {
    int q = idx - A; w3h[q] = (_Float16)e3w[q];
  } else if (idx < A + Bc + C) {
    int q = idx - A - Bc; n2wh[q] = (_Float16)n2w[q];
  } else if (idx < A + Bc + C + Dn) {
    int q = idx - A - Bc - C;
    int n = q / 544, k = q % 544;
    n1wh[q] = (k < 520) ? (_Float16)n1w[n*520 + k] : (_Float16)0.0f;
  }
}

// ----------------------------------------------------- edge (fused MLP) ----
// R14: ONE (b,i) per WG (2048 WGs), 64 rows. 8 waves, wave = 64j x 64n,
// acc[4][4] = 64 AGPR (half of R11) -> ~195/256 unified regs => room for
// 2-deep double-buffered prefetch of BOTH weight stream and af LDS reads
// (the depth R12 proved impossible at acc=128: spilled).
// H1 and H2 in SEPARATE 64 KB LDS regions (no overwrite hazard; one fewer
// barrier). Orientation/layout/build identical to R11 (proven):
// A-frag = H rows (LDS), B-frag = W rows (global/L2); D: row=j, col=n.
// byte(row,k) = (row*1024 + k*2) ^ ((row&7)<<4), row < 64.

__device__ __forceinline__ void mlp_layer64(const char* hb,
                                            const _Float16* __restrict__ wbase0,
                                            const float* __restrict__ biasp,
                                            int wcol, int lr, int lg,
                                            f32x4 acc[4][4]) {
  #pragma unroll
  for (int nt = 0; nt < 4; ++nt) {
    float bz = biasp[wcol + nt*16 + lr];
    #pragma unroll
    for (int mt = 0; mt < 4; ++mt) {
      acc[mt][nt][0] = bz; acc[mt][nt][1] = bz;
      acc[mt][nt][2] = bz; acc[mt][nt][3] = bz;
    }
  }
  const _Float16* bbase = wbase0 + (size_t)(wcol + lr)*NH + lg*8;
  f16x8 bfp0[4], bfp1[4];
  #pragma unroll
  for (int nt = 0; nt < 4; ++nt) {
    bfp0[nt] = *(const f16x8*)(bbase + nt*16*NH);
    bfp1[nt] = *(const f16x8*)(bbase + nt*16*NH + 32);
  }
  f16x8 af0[4], af1[4];
  #pragma unroll
  for (int mt = 0; mt < 4; ++mt) {
    const int row = mt*16 + lr;
    af0[mt] = *(const f16x8*)(hb + ((row*1024 + lg*16) ^ ((row & 7) << 4)));
    af1[mt] = *(const f16x8*)(hb + ((row*1024 + 64 + lg*16) ^ ((row & 7) << 4)));
  }
  for (int kk = 0; kk < 16; ++kk) {
    f16x8 bf[4], afc[4];
    #pragma unroll
    for (int nt = 0; nt < 4; ++nt) { bf[nt] = bfp0[nt]; bfp0[nt] = bfp1[nt]; }
    #pragma unroll
    for (int mt = 0; mt < 4; ++mt) { afc[mt] = af0[mt]; af0[mt] = af1[mt]; }
    if (kk < 14) {
      #pragma unroll
      for (int nt = 0; nt < 4; ++nt)
        bfp1[nt] = *(const f16x8*)(bbase + nt*16*NH + (kk+2)*32);
      #pragma unroll
      for (int mt = 0; mt < 4; ++mt) {
        const int row = mt*16 + lr;
        af1[mt] = *(const f16x8*)(hb + ((row*1024 + (kk+2)*64 + lg*16) ^ ((row & 7) << 4)));
      }
    }
    __builtin_amdgcn_s_setprio(1);
    #pragma unroll
    for (int mt = 0; mt < 4; ++mt)
      #pragma unroll
      for (int nt = 0; nt < 4; ++nt)
        acc[mt][nt] = __builtin_amdgcn_mfma_f32_16x16x32_f16(afc[mt], bf[nt], acc[mt][nt], 0, 0, 0);
    __builtin_amdgcn_s_setprio(0);
  }
}

__global__ __launch_bounds__(512, 1) void edge_fused(
    const _Float16* __restrict__ u16, const _Float16* __restrict__ v16,
    const _Float16* __restrict__ w2h, const _Float16* __restrict__ w3h,
    const float* __restrict__ e2b, const float* __restrict__ e3b,
    const float* __restrict__ maskp, const float* __restrict__ cntp,
    const float* __restrict__ lng, const float* __restrict__ lnb,
    _Float16* __restrict__ nodein) {
  __shared__ __align__(16) char lds[131072];   // H1 @0 (64KB), H2 @65536
  __shared__ float em_s[64];
  __shared__ float red_s[16];
  __shared__ float stat_s[2];

  const int t = threadIdx.x;
  const int bi = blockIdx.x;           // one (b,i) per WG
  const int b = bi >> 6;
  const int iq = bi & 63;
  const int w = t >> 6, l = t & 63, lr = l & 15, lg = l >> 4;
  const int wcol = w * 64;
  char* h1 = lds;
  char* h2 = lds + 65536;

  if (t < 64) em_s[t] = maskp[(size_t)b*64 + t];

  // ---- build H1 (conflict-free): lane t -> row t>>3, 16B slot t&7
  {
    const int jrow = t >> 3;    // j 0..63
    const int slot = t & 7;
    const _Float16* vrow = v16 + ((size_t)(b*64 + jrow))*NH;
    const _Float16* up   = u16 + (size_t)bi*NH;
    #pragma unroll
    for (int e = 0; e < 8; ++e) {
      const int kelem = e*64 + slot*8;
      f16x8 vv = *(const f16x8*)(vrow + kelem);
      f16x8 uu = *(const f16x8*)(up + kelem);
      f16x8 hv;
      #pragma unroll
      for (int q = 0; q < 8; ++q) {
        _Float16 x = uu[q] + vv[q];
        hv[q] = x > (_Float16)0 ? x : (_Float16)0;
      }
      *(f16x8*)(h1 + ((jrow*1024 + kelem*2) ^ ((jrow & 7) << 4))) = hv;
    }
  }
  __syncthreads();

  f32x4 acc[4][4];   // [mt][nt]; j = mt*16 + lg*4 + r, n = wcol + nt*16 + lr

  // ---- layer 2: acc = H1 @ W2^T + b2
  mlp_layer64(h1, w2h, e2b, wcol, lr, lg, acc);

  // ---- H2 = relu(acc) -> separate region (no hazard with H1 readers)
  #pragma unroll
  for (int mt = 0; mt < 4; ++mt)
    #pragma unroll
    for (int nt = 0; nt < 4; ++nt)
      #pragma unroll
      for (int r = 0; r < 4; ++r) {
        int row = mt*16 + lg*4 + r;
        int cc = wcol + nt*16 + lr;
        *(_Float16*)(h2 + ((row*1024 + cc*2) ^ ((row & 7) << 4))) =
            (_Float16)fmaxf(acc[mt][nt][r], 0.0f);
      }
  __syncthreads();   // H2 complete

  // ---- layer 3: acc = H2 @ W3^T + b3
  mlp_layer64(h2, w3h, e3b, wcol, lr, lg, acc);

  // ---- relu + mask-weighted j-sum (wave's 64 j = whole group)
  float csum[4] = {0.f, 0.f, 0.f, 0.f};
  #pragma unroll
  for (int mt = 0; mt < 4; ++mt) {
    float em0 = em_s[mt*16 + lg*4 + 0];
    float em1 = em_s[mt*16 + lg*4 + 1];
    float em2 = em_s[mt*16 + lg*4 + 2];
    float em3 = em_s[mt*16 + lg*4 + 3];
    #pragma unroll
    for (int nt = 0; nt < 4; ++nt) {
      csum[nt] += em0 * fmaxf(acc[mt][nt][0], 0.f)
                + em1 * fmaxf(acc[mt][nt][1], 0.f)
                + em2 * fmaxf(acc[mt][nt][2], 0.f)
                + em3 * fmaxf(acc[mt][nt][3], 0.f);
    }
  }
  #pragma unroll
  for (int nt = 0; nt < 4; ++nt) {
    csum[nt] += __shfl_xor(csum[nt], 16);
    csum[nt] += __shfl_xor(csum[nt], 32);
  }
  float scale = em_s[iq] / cntp[b];
  __syncthreads();   // all H1 reads long done; reuse h1 region as agg[512]
  float* aggs = (float*)lds;
  if (lg == 0) {
    #pragma unroll
    for (int nt = 0; nt < 4; ++nt)
      aggs[wcol + nt*16 + lr] = csum[nt] * scale;
  }
  __syncthreads();

  // ---- LayerNorm + nodein write
  {
    float a = aggs[t];
    float s1 = a, s2 = a * a;
    #pragma unroll
    for (int off = 1; off < 64; off <<= 1) {
      s1 += __shfl_xor(s1, off);
      s2 += __shfl_xor(s2, off);
    }
    if (l == 0) { red_s[w] = s1; red_s[8 + w] = s2; }
    __syncthreads();
    if (t == 0) {
      float S1 = 0.f, S2 = 0.f;
      #pragma unroll
      for (int q = 0; q < 8; ++q) { S1 += red_s[q]; S2 += red_s[8 + q]; }
      float mean = S1 * (1.0f/512.0f);
      float var = S2 * (1.0f/512.0f) - mean * mean;
      stat_s[0] = mean;
      stat_s[1] = rsqrtf(var + 1e-5f);
    }
    __syncthreads();
    float nrm = (a - stat_s[0]) * stat_s[1] * lng[t] + lnb[t];
    nodein[(size_t)bi*NKP + 4 + t] = (_Float16)nrm;
  }
}

// ---------------------------------------------------------------- node ----
// Fused node MLP + pooling (R12-proven): one block per b, 512 thr = 8 waves.

__global__ __launch_bounds__(512, 1) void node_fused(
    const _Float16* __restrict__ nodein,
    const _Float16* __restrict__ n1wh, const float* __restrict__ n1b,
    const _Float16* __restrict__ n2wh, const float* __restrict__ n2b,
    const float* __restrict__ maskp, const float* __restrict__ cntp,
    float* __restrict__ xfeat) {
  __shared__ __align__(16) char lds[65536];
  __shared__ float em_s[64];
  const int b = blockIdx.x;
  const int t = threadIdx.x;
  const int w = t >> 6, l = t & 63, lr = l & 15, lg = l >> 4;

  if (t < 64) em_s[t] = maskp[(size_t)b*64 + t];

  {
    const int wcol = w * 64;
    f32x4 acc[4][4];
    #pragma unroll
    for (int nt = 0; nt < 4; ++nt) {
      float bz = n1b[wcol + nt*16 + lr];
      #pragma unroll
      for (int mt = 0; mt < 4; ++mt) {
        acc[mt][nt][0] = bz; acc[mt][nt][1] = bz;
        acc[mt][nt][2] = bz; acc[mt][nt][3] = bz;
      }
    }
    const _Float16* abase = nodein + ((size_t)(b*64 + lr))*NKP + lg*8;
    const _Float16* bbase = n1wh + (size_t)(wcol + lr)*NKP + lg*8;
    for (int kk = 0; kk < 17; ++kk) {
      f16x8 af[4], bf[4];
      #pragma unroll
      for (int mt = 0; mt < 4; ++mt)
        af[mt] = *(const f16x8*)(abase + ((size_t)mt*16)*NKP + kk*32);
      #pragma unroll
      for (int nt = 0; nt < 4; ++nt)
        bf[nt] = *(const f16x8*)(bbase + ((size_t)nt*16)*NKP + kk*32);
      #pragma unroll
      for (int mt = 0; mt < 4; ++mt)
        #pragma unroll
        for (int nt = 0; nt < 4; ++nt)
          acc[mt][nt] = __builtin_amdgcn_mfma_f32_16x16x32_f16(af[mt], bf[nt], acc[mt][nt], 0, 0, 0);
    }
    #pragma unroll
    for (int mt = 0; mt < 4; ++mt)
      #pragma unroll
      for (int nt = 0; nt < 4; ++nt)
        #pragma unroll
        for (int r = 0; r < 4; ++r) {
          int row = mt*16 + lg*4 + r;
          int cc = wcol + nt*16 + lr;
          *(_Float16*)(lds + ((row*1024 + cc*2) ^ ((row & 7) << 4))) =
              (_Float16)fmaxf(acc[mt][nt][r], 0.0f);
        }
  }
  __syncthreads();

  {
    const int wcol = w * 32;
    f32x4 acc[4][2];
    #pragma unroll
    for (int nt = 0; nt < 2; ++nt) {
      float bz = n2b[wcol + nt*16 + lr];
      #pragma unroll
      for (int mt = 0; mt < 4; ++mt) {
        acc[mt][nt][0] = bz; acc[mt][nt][1] = bz;
        acc[mt][nt][2] = bz; acc[mt][nt][3] = bz;
      }
    }
    const _Float16* bbase = n2wh + (size_t)(wcol + lr)*NH + lg*8;
    for (int kk = 0; kk < 16; ++kk) {
      f16x8 bf[2];
      #pragma unroll
      for (int nt = 0; nt < 2; ++nt)
        bf[nt] = *(const f16x8*)(bbase + nt*16*NH + kk*32);
      f16x8 af[4];
      #pragma unroll
      for (int mt = 0; mt < 4; ++mt) {
        const int row = mt*16 + lr;
        af[mt] = *(const f16x8*)(lds + ((row*1024 + kk*64 + lg*16) ^ ((row & 7) << 4)));
      }
      #pragma unroll
      for (int mt = 0; mt < 4; ++mt)
        #pragma unroll
        for (int nt = 0; nt < 2; ++nt)
          acc[mt][nt] = __builtin_amdgcn_mfma_f32_16x16x32_f16(af[mt], bf[nt], acc[mt][nt], 0, 0, 0);
    }
    float sumv[2] = {0.f, 0.f};
    float mxv[2] = {-1e9f, -1e9f};
    #pragma unroll
    for (int mt = 0; mt < 4; ++mt)
      #pragma unroll
      for (int r = 0; r < 4; ++r) {
        float em = em_s[mt*16 + lg*4 + r];
        #pragma unroll
        for (int nt = 0; nt < 2; ++nt) {
          float v = acc[mt][nt][r];
          sumv[nt] += em * v;
          mxv[nt] = fmaxf(mxv[nt], (em != 0.f) ? v : -1e9f);
        }
      }
    #pragma unroll
    for (int nt = 0; nt < 2; ++nt) {
      sumv[nt] += __shfl_xor(sumv[nt], 16);
      sumv[nt] += __shfl_xor(sumv[nt], 32);
      mxv[nt] = fmaxf(mxv[nt], __shfl_xor(mxv[nt], 16));
      mxv[nt] = fmaxf(mxv[nt], __shfl_xor(mxv[nt], 32));
    }
    float cnt = cntp[b];
    if (lg == 0) {
      #pragma unroll
      for (int nt = 0; nt < 2; ++nt) {
        int col = wcol + nt*16 + lr;
        xfeat[b*1024 + 512 + col] = sumv[nt] / cnt;
        xfeat[b*1024 + 768 + col] = mxv[nt];
      }
    }
  }
}

// ----------------------------------------------------------------- heads ----

__global__ __launch_bounds__(256) void heads_g1(
    const float* __restrict__ xfeat,
    const float* __restrict__ mu1w, const float* __restrict__ s1w,
    float* __restrict__ part) {
  __shared__ __align__(16) float xs[256];
  const int b = blockIdx.x, h = blockIdx.y, ks = blockIdx.z;
  const int t = threadIdx.x;
  xs[t] = xfeat[b*1024 + ks*256 + t];
  __syncthreads();
  const float* wr = (h ? s1w : mu1w) + (size_t)t*1024 + ks*256;
  float a = 0.f;
  #pragma unroll 8
  for (int k = 0; k < 256; k += 4) {
    float4 ww = *(const float4*)(wr + k);
    float4 xx = *(const float4*)(xs + k);
    a += ww.x*xx.x + ww.y*xx.y + ww.z*xx.z + ww.w*xx.w;
  }
  part[(((size_t)(b*2 + h))*256 + t)*4 + ks] = a;
}

__global__ __launch_bounds__(256) void heads_g23(
    const float* __restrict__ part,
    const float* __restrict__ mu1b, const float* __restrict__ s1b,
    const float* __restrict__ mu2w, const float* __restrict__ mu2b,
    const float* __restrict__ s2w, const float* __restrict__ s2b,
    const float* __restrict__ mu3w, const float* __restrict__ mu3b,
    const float* __restrict__ s3w, const float* __restrict__ s3b,
    float* __restrict__ outp) {
  __shared__ __align__(16) float h1s[256];
  __shared__ __align__(16) float h2s[128];
  const int b = blockIdx.x, h = blockIdx.y;
  const int t = threadIdx.x;
  {
    float4 pp = *(const float4*)(part + (((size_t)(b*2 + h))*256 + t)*4);
    float a = pp.x + pp.y + pp.z + pp.w + (h ? s1b : mu1b)[t];
    h1s[t] = fmaxf(a, 0.f);
  }
  __syncthreads();
  {
    const int o = t >> 1, half = t & 1;
    const float* wr = (h ? s2w : mu2w) + (size_t)o*256 + half*128;
    const float* hp = h1s + half*128;
    float a = 0.f;
    #pragma unroll 8
    for (int k = 0; k < 128; k += 4) {
      float4 ww = *(const float4*)(wr + k);
      float4 hh = *(const float4*)(hp + k);
      a += ww.x*hh.x + ww.y*hh.y + ww.z*hh.z + ww.w*hh.w;
    }
    a += __shfl_xor(a, 1);
    if (half == 0) h2s[o] = fmaxf(a + (h ? s2b : mu2b)[o], 0.f);
  }
  __syncthreads();
  if (t < 64) {
    const int o = t >> 5, lane = t & 31;
    const float* wr = (h ? s3w : mu3w) + o*128 + lane*4;
    const float* hp = h2s + lane*4;
    float4 ww = *(const float4*)wr;
    float4 hh = *(const float4*)hp;
    float a = ww.x*hh.x + ww.y*hh.y + ww.z*hh.z + ww.w*hh.w;
    #pragma unroll
    for (int off = 1; off < 32; off <<= 1) a += __shfl_xor(a, off);
    if (lane == 0) {
      a += (h ? s3b : mu3b)[o];
      if (h == 0) {
        outp[b*2 + o] = a;
      } else {
        float spv = (a > 0.f) ? (a + log1pf(expf(-a))) : log1pf(expf(a));
        outp[64 + b*2 + o] = fminf(fmaxf(spv + 0.001f, 0.1f), 2.0f);
      }
    }
  }
}

// --------------------------------------------------------------- launch ----

extern "C" void kernel_launch(void* const* d_in, const int* in_sizes, int n_in,
                              void* d_out, int out_size, void* d_ws, size_t ws_size,
                              hipStream_t stream) {
  const float* state  = (const float*)d_in[0];
  const float* obs    = (const float*)d_in[1];
  const float* layerw = (const float*)d_in[2];
  const float* layerb = (const float*)d_in[3];
  const float* e1w    = (const float*)d_in[4];
  const float* e1b    = (const float*)d_in[5];
  const float* e2w    = (const float*)d_in[6];
  const float* e2b    = (const float*)d_in[7];
  const float* e3w    = (const float*)d_in[8];
  const float* e3b    = (const float*)d_in[9];
  const float* lng    = (const float*)d_in[10];
  const float* lnb    = (const float*)d_in[11];
  const float* n1w    = (const float*)d_in[12];
  const float* n1b    = (const float*)d_in[13];
  const float* n2w    = (const float*)d_in[14];
  const float* n2b    = (const float*)d_in[15];
  const float* mu1w   = (const float*)d_in[16];
  const float* mu1b   = (const float*)d_in[17];
  const float* mu2w   = (const float*)d_in[18];
  const float* mu2b   = (const float*)d_in[19];
  const float* mu3w   = (const float*)d_in[20];
  const float* mu3b   = (const float*)d_in[21];
  const float* s1w    = (const float*)d_in[22];
  const float* s1b    = (const float*)d_in[23];
  const float* s2w    = (const float*)d_in[24];
  const float* s2b    = (const float*)d_in[25];
  const float* s3w    = (const float*)d_in[26];
  const float* s3b    = (const float*)d_in[27];
  float* outp = (float*)d_out;

  char* p = (char*)d_ws;
  auto alloc = [&](size_t bytes) {
    char* r = p;
    p += (bytes + 255) & ~(size_t)255;
    return r;
  };
  float*    maskp   = (float*)alloc((size_t)2048*4);
  float*    cntp    = (float*)alloc((size_t)32*4);
  _Float16* u16     = (_Float16*)alloc((size_t)2048*512*2);
  _Float16* v16     = (_Float16*)alloc((size_t)2048*512*2);
  _Float16* w2h     = (_Float16*)alloc((size_t)512*512*2);
  _Float16* w3h     = (_Float16*)alloc((size_t)512*512*2);
  _Float16* nodein  = (_Float16*)alloc((size_t)2048*544*2);
  _Float16* n1wh    = (_Float16*)alloc((size_t)512*544*2);
  _Float16* n2wh    = (_Float16*)alloc((size_t)256*512*2);
  float*    xfeat   = (float*)alloc((size_t)32*1024*4);
  float*    hpart   = (float*)alloc((size_t)32*2*256*4*4);

  prep_fused<<<32, 512, 0, stream>>>(obs, state, e1w, e1b, layerw, layerb,
                                     maskp, cntp, u16, v16, nodein, xfeat);
  prep_w16_kernel<<<3648, 256, 0, stream>>>(e2w, e3w, n2w, n1w, w2h, w3h, n2wh, n1wh);

  edge_fused<<<2048, 512, 0, stream>>>(u16, v16, w2h, w3h, e2b, e3b,
                                       maskp, cntp, lng, lnb, nodein);

  node_fused<<<32, 512, 0, stream>>>(nodein, n1wh, n1b, n2wh, n2b,
                                     maskp, cntp, xfeat);
  heads_g1<<<dim3(32, 2, 4), 256, 0, stream>>>(xfeat, mu1w, s1w, hpart);
  heads_g23<<<dim3(32, 2), 256, 0, stream>>>(hpart, mu1b, s1b, mu2w, mu2b,
                                             s2w, s2b, mu3w, mu3b, s3w, s3b, outp);
}

// Round 15
// 207.358 us; speedup vs baseline: 1.5544x; 1.5544x over previous
//
#include <hip/hip_runtime.h>
#include <hip/hip_fp16.h>

typedef _Float16 f16x8 __attribute__((ext_vector_type(8)));
typedef _Float16 f16x4 __attribute__((ext_vector_type(4)));
typedef float f32x4 __attribute__((ext_vector_type(4)));

#define NB 32
#define NK 64
#define ND 4
#define NH 512
#define NKP 544   // node-input K (520) padded to 17*32

// ---------------------------------------------------------------- prep ----
// Fused: obs/mask/cnt prep + u/v (layer-1 low-rank) + state-feature.

__global__ __launch_bounds__(512) void prep_fused(
    const float* __restrict__ obs, const float* __restrict__ state,
    const float* __restrict__ e1w, const float* __restrict__ e1b,
    const float* __restrict__ lw, const float* __restrict__ lb,
    float* __restrict__ maskp, float* __restrict__ cntp,
    _Float16* __restrict__ u16, _Float16* __restrict__ v16,
    _Float16* __restrict__ nodein, float* __restrict__ xfeat) {
  __shared__ __align__(16) float os[64][4];
  __shared__ float st[4];
  const int b = blockIdx.x;
  const int t = threadIdx.x;
  if (t < 4) st[t] = state[b*4 + t];
  if (t < 64) {
    float o0 = obs[(b*4 + 0)*64 + t];
    float o1 = obs[(b*4 + 1)*64 + t];
    float o2 = obs[(b*4 + 2)*64 + t];
    float o3 = obs[(b*4 + 3)*64 + t];
    os[t][0] = o0; os[t][1] = o1; os[t][2] = o2; os[t][3] = o3;
    float s = fabsf(o0) + fabsf(o1) + fabsf(o2) + fabsf(o3);
    float m = (s != 0.0f) ? 1.0f : 0.0f;
    maskp[b*64 + t] = m;
    float c = m;
    #pragma unroll
    for (int off = 1; off < 64; off <<= 1) c += __shfl_xor(c, off);
    if (t == 0) cntp[b] = fmaxf(c, 1e-6f);
    _Float16* nrow = nodein + (size_t)(b*64 + t)*NKP;
    nrow[0] = (_Float16)o0; nrow[1] = (_Float16)o1;
    nrow[2] = (_Float16)o2; nrow[3] = (_Float16)o3;
    nrow[516] = (_Float16)state[b*4 + 0];
    nrow[517] = (_Float16)state[b*4 + 1];
    nrow[518] = (_Float16)state[b*4 + 2];
    nrow[519] = (_Float16)state[b*4 + 3];
    #pragma unroll
    for (int k2 = 520; k2 < 544; ++k2) nrow[k2] = (_Float16)0.0f;
  }
  __syncthreads();
  // u/v for all 64 (b,i): thread t = channel, weight row cached in regs
  {
    const float* wr = e1w + t*8;
    float4 wa = *(const float4*)wr;
    float4 wb = *(const float4*)(wr + 4);
    float bias = e1b[t];
    for (int j = 0; j < 64; ++j) {
      float4 ov = *(const float4*)os[j];
      float u = wa.x*ov.x + wa.y*ov.y + wa.z*ov.z + wa.w*ov.w + bias;
      float v = wb.x*ov.x + wb.y*ov.y + wb.z*ov.z + wb.w*ov.w;
      const size_t bi = (size_t)b*64 + j;
      u16[bi*NH + t] = (_Float16)u;
      v16[bi*NH + t] = (_Float16)v;
    }
  }
  // state feature
  {
    const float* wl = lw + t*4;
    float hv = wl[0]*st[0] + wl[1]*st[1] + wl[2]*st[2] + wl[3]*st[3] + lb[t];
    xfeat[b*1024 + t] = fmaxf(hv, 0.0f);
  }
}

__global__ void prep_w16_kernel(const float* __restrict__ e2w,
                                const float* __restrict__ e3w,
                                const float* __restrict__ n2w,
                                const float* __restrict__ n1w,
                                _Float16* __restrict__ w2h,
                                _Float16* __restrict__ w3h,
                                _Float16* __restrict__ n2wh,
                                _Float16* __restrict__ n1wh) {
  int idx = blockIdx.x * blockDim.x + threadIdx.x;
  const int A = 512*512, Bc = 512*512, C = 256*512, Dn = 512*544;
  if (idx < A) {
    w2h[idx] = (_Float16)e2w[idx];
  } else if (idx < A + Bc) {
    int q = idx - A; w3h[q] = (_Float16)e3w[q];
  } else if (idx < A + Bc + C) {
    int q = idx - A - Bc; n2wh[q] = (_Float16)n2w[q];
  } else if (idx < A + Bc + C + Dn) {
    int q = idx - A - Bc - C;
    int n = q / 544, k = q % 544;
    n1wh[q] = (k < 520) ? (_Float16)n1w[n*520 + k] : (_Float16)0.0f;
  }
}

// ----------------------------------------------------- edge (fused MLP) ----
// R11/R13 kernel verbatim (best measured: edge 173 us, MfmaUtil 35,
// 108 VGPR + 128 AGPR = 236/256 unified budget). Structure law from
// R5/R8/R14: 128 rows/WG is the arithmetic-intensity optimum; smaller
// tiles lose to weight streaming, larger don't fit 160 KB LDS.

__device__ __forceinline__ void mlp_layer(const char* hb,
                                          const _Float16* __restrict__ wbase0,
                                          const float* __restrict__ biasp,
                                          int wcol, int lr, int lg,
                                          f32x4 acc[8][4]) {
  #pragma unroll
  for (int nt = 0; nt < 4; ++nt) {
    float bz = biasp[wcol + nt*16 + lr];
    #pragma unroll
    for (int mt = 0; mt < 8; ++mt) {
      acc[mt][nt][0] = bz; acc[mt][nt][1] = bz;
      acc[mt][nt][2] = bz; acc[mt][nt][3] = bz;
    }
  }
  const _Float16* bbase = wbase0 + (size_t)(wcol + lr)*NH + lg*8;
  f16x8 bfp[4];
  #pragma unroll
  for (int nt = 0; nt < 4; ++nt)
    bfp[nt] = *(const f16x8*)(bbase + nt*16*NH);

  // prefetch lo-half (mt 0..3) for kk=0
  f16x8 aflo[4];
  #pragma unroll
  for (int mt = 0; mt < 4; ++mt) {
    const int row = mt*16 + lr;
    aflo[mt] = *(const f16x8*)(hb + ((row*1024 + lg*16) ^ ((row & 7) << 4)));
  }

  for (int kk = 0; kk < 16; ++kk) {
    f16x8 bf[4];
    #pragma unroll
    for (int nt = 0; nt < 4; ++nt) bf[nt] = bfp[nt];
    if (kk < 15) {
      #pragma unroll
      for (int nt = 0; nt < 4; ++nt)
        bfp[nt] = *(const f16x8*)(bbase + nt*16*NH + (kk+1)*32);
    }
    // read hi-half (mt 4..7) of current kk, then MFMA lo-half
    f16x8 afhi[4];
    #pragma unroll
    for (int mt = 0; mt < 4; ++mt) {
      const int row = (mt + 4)*16 + lr;
      afhi[mt] = *(const f16x8*)(hb + ((row*1024 + kk*64 + lg*16) ^ ((row & 7) << 4)));
    }
    __builtin_amdgcn_s_setprio(1);
    #pragma unroll
    for (int mt = 0; mt < 4; ++mt)
      #pragma unroll
      for (int nt = 0; nt < 4; ++nt)
        acc[mt][nt] = __builtin_amdgcn_mfma_f32_16x16x32_f16(aflo[mt], bf[nt], acc[mt][nt], 0, 0, 0);
    __builtin_amdgcn_s_setprio(0);
    // read lo-half of next kk, then MFMA hi-half
    f16x8 aflon[4];
    if (kk < 15) {
      #pragma unroll
      for (int mt = 0; mt < 4; ++mt) {
        const int row = mt*16 + lr;
        aflon[mt] = *(const f16x8*)(hb + ((row*1024 + (kk+1)*64 + lg*16) ^ ((row & 7) << 4)));
      }
    }
    __builtin_amdgcn_s_setprio(1);
    #pragma unroll
    for (int mt = 0; mt < 4; ++mt)
      #pragma unroll
      for (int nt = 0; nt < 4; ++nt)
        acc[mt + 4][nt] = __builtin_amdgcn_mfma_f32_16x16x32_f16(afhi[mt], bf[nt], acc[mt + 4][nt], 0, 0, 0);
    __builtin_amdgcn_s_setprio(0);
    #pragma unroll
    for (int mt = 0; mt < 4; ++mt) aflo[mt] = aflon[mt];
  }
}

__global__ __launch_bounds__(512, 1) void edge_fused(
    const _Float16* __restrict__ u16, const _Float16* __restrict__ v16,
    const _Float16* __restrict__ w2h, const _Float16* __restrict__ w3h,
    const float* __restrict__ e2b, const float* __restrict__ e3b,
    const float* __restrict__ maskp, const float* __restrict__ cntp,
    const float* __restrict__ lng, const float* __restrict__ lnb,
    _Float16* __restrict__ nodein) {
  __shared__ __align__(16) char lds[131072];
  __shared__ float em_s[64];
  __shared__ float red_s[16];
  __shared__ float stat_s[2];

  const int t = threadIdx.x;
  const int bi0 = blockIdx.x * 2;      // two consecutive (b,i), same b
  const int b = bi0 >> 6;
  const int w = t >> 6, l = t & 63, lr = l & 15, lg = l >> 4;
  const int wcol = w * 64;

  if (t < 64) em_s[t] = maskp[(size_t)b*64 + t];

  // ---- build H1 (conflict-free): lane t -> row t>>3, 16B slot t&7.
  {
    const int jrow = t >> 3;    // j 0..63
    const int slot = t & 7;
    const _Float16* vrow = v16 + ((size_t)(b*64 + jrow))*NH;
    const _Float16* u0p  = u16 + (size_t)bi0*NH;
    const _Float16* u1p  = u16 + (size_t)(bi0 + 1)*NH;
    #pragma unroll
    for (int e = 0; e < 8; ++e) {
      const int kelem = e*64 + slot*8;
      f16x8 vv = *(const f16x8*)(vrow + kelem);
      f16x8 u0 = *(const f16x8*)(u0p + kelem);
      f16x8 u1 = *(const f16x8*)(u1p + kelem);
      f16x8 h0, h1;
      #pragma unroll
      for (int q = 0; q < 8; ++q) {
        _Float16 x0 = u0[q] + vv[q];
        _Float16 x1 = u1[q] + vv[q];
        h0[q] = x0 > (_Float16)0 ? x0 : (_Float16)0;
        h1[q] = x1 > (_Float16)0 ? x1 : (_Float16)0;
      }
      const int bc = kelem*2;
      const int r1 = 64 + jrow;
      *(f16x8*)(lds + ((jrow*1024 + bc) ^ ((jrow & 7) << 4))) = h0;
      *(f16x8*)(lds + ((r1*1024 + bc) ^ ((r1 & 7) << 4))) = h1;
    }
  }
  __syncthreads();

  f32x4 acc[8][4];   // [mt][nt]; j-row = mt*16 + lg*4 + r, n = wcol+nt*16+lr

  // ---- layer 2: acc = H1 @ W2^T + b2
  mlp_layer(lds, w2h, e2b, wcol, lr, lg, acc);
  __syncthreads();   // all waves done reading H1

  // ---- H2 = relu(acc) overwrites the same LDS buffer (same layout)
  #pragma unroll
  for (int mt = 0; mt < 8; ++mt)
    #pragma unroll
    for (int nt = 0; nt < 4; ++nt)
      #pragma unroll
      for (int r = 0; r < 4; ++r) {
        int row = mt*16 + lg*4 + r;
        int cc = wcol + nt*16 + lr;
        *(_Float16*)(lds + ((row*1024 + cc*2) ^ ((row & 7) << 4))) =
            (_Float16)fmaxf(acc[mt][nt][r], 0.0f);
      }
  __syncthreads();   // H2 complete

  // ---- layer 3: acc = H2 @ W3^T + b3
  mlp_layer(lds, w3h, e3b, wcol, lr, lg, acc);

  // ---- relu + mask-weighted sum over j; rows 0-63 -> bi0, 64-127 -> bi0+1
  float csum[2][4] = {{0.f,0.f,0.f,0.f},{0.f,0.f,0.f,0.f}};
  #pragma unroll
  for (int mt = 0; mt < 8; ++mt) {
    const int g = mt >> 2;
    float em0 = em_s[(mt&3)*16 + lg*4 + 0];
    float em1 = em_s[(mt&3)*16 + lg*4 + 1];
    float em2 = em_s[(mt&3)*16 + lg*4 + 2];
    float em3 = em_s[(mt&3)*16 + lg*4 + 3];
    #pragma unroll
    for (int nt = 0; nt < 4; ++nt) {
      csum[g][nt] += em0 * fmaxf(acc[mt][nt][0], 0.f)
                   + em1 * fmaxf(acc[mt][nt][1], 0.f)
                   + em2 * fmaxf(acc[mt][nt][2], 0.f)
                   + em3 * fmaxf(acc[mt][nt][3], 0.f);
    }
  }
  #pragma unroll
  for (int g = 0; g < 2; ++g)
    #pragma unroll
    for (int nt = 0; nt < 4; ++nt) {
      csum[g][nt] += __shfl_xor(csum[g][nt], 16);
      csum[g][nt] += __shfl_xor(csum[g][nt], 32);
    }
  float cnt = cntp[b];
  __syncthreads();   // done with H2 reads; reuse lds as agg[2][512]
  float* aggs = (float*)lds;
  if (lg == 0) {
    #pragma unroll
    for (int g = 0; g < 2; ++g) {
      int big = bi0 + g;
      float sc = em_s[big & 63] / cnt;
      #pragma unroll
      for (int nt = 0; nt < 4; ++nt)
        aggs[g*512 + wcol + nt*16 + lr] = csum[g][nt] * sc;
    }
  }
  __syncthreads();

  // ---- LayerNorm (both rows) + nodein write
  for (int g = 0; g < 2; ++g) {
    float a = aggs[g*512 + t];
    float s1 = a, s2 = a * a;
    #pragma unroll
    for (int off = 1; off < 64; off <<= 1) {
      s1 += __shfl_xor(s1, off);
      s2 += __shfl_xor(s2, off);
    }
    if (l == 0) { red_s[w] = s1; red_s[8 + w] = s2; }
    __syncthreads();
    if (t == 0) {
      float S1 = 0.f, S2 = 0.f;
      #pragma unroll
      for (int q = 0; q < 8; ++q) { S1 += red_s[q]; S2 += red_s[8 + q]; }
      float mean = S1 * (1.0f/512.0f);
      float var = S2 * (1.0f/512.0f) - mean * mean;
      stat_s[0] = mean;
      stat_s[1] = rsqrtf(var + 1e-5f);
    }
    __syncthreads();
    float nrm = (a - stat_s[0]) * stat_s[1] * lng[t] + lnb[t];
    nodein[(size_t)(bi0 + g)*NKP + 4 + t] = (_Float16)nrm;
    __syncthreads();   // protect red_s/stat_s before next g
  }
}

// ---------------------------------------------------------------- node ----
// Fused node MLP + pooling (R12-proven): one block per b, 512 thr = 8 waves.

__global__ __launch_bounds__(512, 1) void node_fused(
    const _Float16* __restrict__ nodein,
    const _Float16* __restrict__ n1wh, const float* __restrict__ n1b,
    const _Float16* __restrict__ n2wh, const float* __restrict__ n2b,
    const float* __restrict__ maskp, const float* __restrict__ cntp,
    float* __restrict__ xfeat) {
  __shared__ __align__(16) char lds[65536];
  __shared__ float em_s[64];
  const int b = blockIdx.x;
  const int t = threadIdx.x;
  const int w = t >> 6, l = t & 63, lr = l & 15, lg = l >> 4;

  if (t < 64) em_s[t] = maskp[(size_t)b*64 + t];

  // ---- layer 1: H[j][c] = relu(nodein_j . n1w_c + b), c in [w*64, w*64+64)
  {
    const int wcol = w * 64;
    f32x4 acc[4][4];
    #pragma unroll
    for (int nt = 0; nt < 4; ++nt) {
      float bz = n1b[wcol + nt*16 + lr];
      #pragma unroll
      for (int mt = 0; mt < 4; ++mt) {
        acc[mt][nt][0] = bz; acc[mt][nt][1] = bz;
        acc[mt][nt][2] = bz; acc[mt][nt][3] = bz;
      }
    }
    const _Float16* abase = nodein + ((size_t)(b*64 + lr))*NKP + lg*8;
    const _Float16* bbase = n1wh + (size_t)(wcol + lr)*NKP + lg*8;
    for (int kk = 0; kk < 17; ++kk) {
      f16x8 af[4], bf[4];
      #pragma unroll
      for (int mt = 0; mt < 4; ++mt)
        af[mt] = *(const f16x8*)(abase + ((size_t)mt*16)*NKP + kk*32);
      #pragma unroll
      for (int nt = 0; nt < 4; ++nt)
        bf[nt] = *(const f16x8*)(bbase + ((size_t)nt*16)*NKP + kk*32);
      #pragma unroll
      for (int mt = 0; mt < 4; ++mt)
        #pragma unroll
        for (int nt = 0; nt < 4; ++nt)
          acc[mt][nt] = __builtin_amdgcn_mfma_f32_16x16x32_f16(af[mt], bf[nt], acc[mt][nt], 0, 0, 0);
    }
    // H relu -> LDS, [row][col] byte = (row*1024 + col*2) ^ ((row&7)<<4)
    #pragma unroll
    for (int mt = 0; mt < 4; ++mt)
      #pragma unroll
      for (int nt = 0; nt < 4; ++nt)
        #pragma unroll
        for (int r = 0; r < 4; ++r) {
          int row = mt*16 + lg*4 + r;
          int cc = wcol + nt*16 + lr;
          *(_Float16*)(lds + ((row*1024 + cc*2) ^ ((row & 7) << 4))) =
              (_Float16)fmaxf(acc[mt][nt][r], 0.0f);
        }
  }
  __syncthreads();

  // ---- layer 2 (no activation) + masked mean/max pool
  {
    const int wcol = w * 32;   // 8 waves x 32 = 256 cols
    f32x4 acc[4][2];
    #pragma unroll
    for (int nt = 0; nt < 2; ++nt) {
      float bz = n2b[wcol + nt*16 + lr];
      #pragma unroll
      for (int mt = 0; mt < 4; ++mt) {
        acc[mt][nt][0] = bz; acc[mt][nt][1] = bz;
        acc[mt][nt][2] = bz; acc[mt][nt][3] = bz;
      }
    }
    const _Float16* bbase = n2wh + (size_t)(wcol + lr)*NH + lg*8;
    for (int kk = 0; kk < 16; ++kk) {
      f16x8 bf[2];
      #pragma unroll
      for (int nt = 0; nt < 2; ++nt)
        bf[nt] = *(const f16x8*)(bbase + nt*16*NH + kk*32);
      f16x8 af[4];
      #pragma unroll
      for (int mt = 0; mt < 4; ++mt) {
        const int row = mt*16 + lr;
        af[mt] = *(const f16x8*)(lds + ((row*1024 + kk*64 + lg*16) ^ ((row & 7) << 4)));
      }
      #pragma unroll
      for (int mt = 0; mt < 4; ++mt)
        #pragma unroll
        for (int nt = 0; nt < 2; ++nt)
          acc[mt][nt] = __builtin_amdgcn_mfma_f32_16x16x32_f16(af[mt], bf[nt], acc[mt][nt], 0, 0, 0);
    }
    // pool over nodes j = mt*16 + lg*4 + r (in-reg) then lanes (shfl 16,32)
    float sumv[2] = {0.f, 0.f};
    float mxv[2] = {-1e9f, -1e9f};
    #pragma unroll
    for (int mt = 0; mt < 4; ++mt)
      #pragma unroll
      for (int r = 0; r < 4; ++r) {
        float em = em_s[mt*16 + lg*4 + r];
        #pragma unroll
        for (int nt = 0; nt < 2; ++nt) {
          float v = acc[mt][nt][r];
          sumv[nt] += em * v;
          mxv[nt] = fmaxf(mxv[nt], (em != 0.f) ? v : -1e9f);
        }
      }
    #pragma unroll
    for (int nt = 0; nt < 2; ++nt) {
      sumv[nt] += __shfl_xor(sumv[nt], 16);
      sumv[nt] += __shfl_xor(sumv[nt], 32);
      mxv[nt] = fmaxf(mxv[nt], __shfl_xor(mxv[nt], 16));
      mxv[nt] = fmaxf(mxv[nt], __shfl_xor(mxv[nt], 32));
    }
    float cnt = cntp[b];
    if (lg == 0) {
      #pragma unroll
      for (int nt = 0; nt < 2; ++nt) {
        int col = wcol + nt*16 + lr;
        xfeat[b*1024 + 512 + col] = sumv[nt] / cnt;
        xfeat[b*1024 + 768 + col] = mxv[nt];
      }
    }
  }
}

// ----------------------------------------------------------------- heads ----

__global__ __launch_bounds__(256) void heads_g1(
    const float* __restrict__ xfeat,
    const float* __restrict__ mu1w, const float* __restrict__ s1w,
    float* __restrict__ part) {
  __shared__ __align__(16) float xs[256];
  const int b = blockIdx.x, h = blockIdx.y, ks = blockIdx.z;
  const int t = threadIdx.x;
  xs[t] = xfeat[b*1024 + ks*256 + t];
  __syncthreads();
  const float* wr = (h ? s1w : mu1w) + (size_t)t*1024 + ks*256;
  float a = 0.f;
  #pragma unroll 8
  for (int k = 0; k < 256; k += 4) {
    float4 ww = *(const float4*)(wr + k);
    float4 xx = *(const float4*)(xs + k);
    a += ww.x*xx.x + ww.y*xx.y + ww.z*xx.z + ww.w*xx.w;
  }
  part[(((size_t)(b*2 + h))*256 + t)*4 + ks] = a;
}

__global__ __launch_bounds__(256) void heads_g23(
    const float* __restrict__ part,
    const float* __restrict__ mu1b, const float* __restrict__ s1b,
    const float* __restrict__ mu2w, const float* __restrict__ mu2b,
    const float* __restrict__ s2w, const float* __restrict__ s2b,
    const float* __restrict__ mu3w, const float* __restrict__ mu3b,
    const float* __restrict__ s3w, const float* __restrict__ s3b,
    float* __restrict__ outp) {
  __shared__ __align__(16) float h1s[256];
  __shared__ __align__(16) float h2s[128];
  const int b = blockIdx.x, h = blockIdx.y;
  const int t = threadIdx.x;
  {
    float4 pp = *(const float4*)(part + (((size_t)(b*2 + h))*256 + t)*4);
    float a = pp.x + pp.y + pp.z + pp.w + (h ? s1b : mu1b)[t];
    h1s[t] = fmaxf(a, 0.f);
  }
  __syncthreads();
  {
    const int o = t >> 1, half = t & 1;
    const float* wr = (h ? s2w : mu2w) + (size_t)o*256 + half*128;
    const float* hp = h1s + half*128;
    float a = 0.f;
    #pragma unroll 8
    for (int k = 0; k < 128; k += 4) {
      float4 ww = *(const float4*)(wr + k);
      float4 hh = *(const float4*)(hp + k);
      a += ww.x*hh.x + ww.y*hh.y + ww.z*hh.z + ww.w*hh.w;
    }
    a += __shfl_xor(a, 1);
    if (half == 0) h2s[o] = fmaxf(a + (h ? s2b : mu2b)[o], 0.f);
  }
  __syncthreads();
  if (t < 64) {
    const int o = t >> 5, lane = t & 31;
    const float* wr = (h ? s3w : mu3w) + o*128 + lane*4;
    const float* hp = h2s + lane*4;
    float4 ww = *(const float4*)wr;
    float4 hh = *(const float4*)hp;
    float a = ww.x*hh.x + ww.y*hh.y + ww.z*hh.z + ww.w*hh.w;
    #pragma unroll
    for (int off = 1; off < 32; off <<= 1) a += __shfl_xor(a, off);
    if (lane == 0) {
      a += (h ? s3b : mu3b)[o];
      if (h == 0) {
        outp[b*2 + o] = a;
      } else {
        float spv = (a > 0.f) ? (a + log1pf(expf(-a))) : log1pf(expf(a));
        outp[64 + b*2 + o] = fminf(fmaxf(spv + 0.001f, 0.1f), 2.0f);
      }
    }
  }
}

// --------------------------------------------------------------- launch ----

extern "C" void kernel_launch(void* const* d_in, const int* in_sizes, int n_in,
                              void* d_out, int out_size, void* d_ws, size_t ws_size,
                              hipStream_t stream) {
  const float* state  = (const float*)d_in[0];
  const float* obs    = (const float*)d_in[1];
  const float* layerw = (const float*)d_in[2];
  const float* layerb = (const float*)d_in[3];
  const float* e1w    = (const float*)d_in[4];
  const float* e1b    = (const float*)d_in[5];
  const float* e2w    = (const float*)d_in[6];
  const float* e2b    = (const float*)d_in[7];
  const float* e3w    = (const float*)d_in[8];
  const float* e3b    = (const float*)d_in[9];
  const float* lng    = (const float*)d_in[10];
  const float* lnb    = (const float*)d_in[11];
  const float* n1w    = (const float*)d_in[12];
  const float* n1b    = (const float*)d_in[13];
  const float* n2w    = (const float*)d_in[14];
  const float* n2b    = (const float*)d_in[15];
  const float* mu1w   = (const float*)d_in[16];
  const float* mu1b   = (const float*)d_in[17];
  const float* mu2w   = (const float*)d_in[18];
  const float* mu2b   = (const float*)d_in[19];
  const float* mu3w   = (const float*)d_in[20];
  const float* mu3b   = (const float*)d_in[21];
  const float* s1w    = (const float*)d_in[22];
  const float* s1b    = (const float*)d_in[23];
  const float* s2w    = (const float*)d_in[24];
  const float* s2b    = (const float*)d_in[25];
  const float* s3w    = (const float*)d_in[26];
  const float* s3b    = (const float*)d_in[27];
  float* outp = (float*)d_out;

  char* p = (char*)d_ws;
  auto alloc = [&](size_t bytes) {
    char* r = p;
    p += (bytes + 255) & ~(size_t)255;
    return r;
  };
  float*    maskp   = (float*)alloc((size_t)2048*4);
  float*    cntp    = (float*)alloc((size_t)32*4);
  _Float16* u16     = (_Float16*)alloc((size_t)2048*512*2);
  _Float16* v16     = (_Float16*)alloc((size_t)2048*512*2);
  _Float16* w2h     = (_Float16*)alloc((size_t)512*512*2);
  _Float16* w3h     = (_Float16*)alloc((size_t)512*512*2);
  _Float16* nodein  = (_Float16*)alloc((size_t)2048*544*2);
  _Float16* n1wh    = (_Float16*)alloc((size_t)512*544*2);
  _Float16* n2wh    = (_Float16*)alloc((size_t)256*512*2);
  float*    xfeat   = (float*)alloc((size_t)32*1024*4);
  float*    hpart   = (float*)alloc((size_t)32*2*256*4*4);

  prep_fused<<<32, 512, 0, stream>>>(obs, state, e1w, e1b, layerw, layerb,
                                     maskp, cntp, u16, v16, nodein, xfeat);
  prep_w16_kernel<<<3648, 256, 0, stream>>>(e2w, e3w, n2w, n1w, w2h, w3h, n2wh, n1wh);

  edge_fused<<<1024, 512, 0, stream>>>(u16, v16, w2h, w3h, e2b, e3b,
                                       maskp, cntp, lng, lnb, nodein);

  node_fused<<<32, 512, 0, stream>>>(nodein, n1wh, n1b, n2wh, n2b,
                                     maskp, cntp, xfeat);
  heads_g1<<<dim3(32, 2, 4), 256, 0, stream>>>(xfeat, mu1w, s1w, hpart);
  heads_g23<<<dim3(32, 2), 256, 0, stream>>>(hpart, mu1b, s1b, mu2w, mu2b,
                                             s2w, s2b, mu3w, mu3b, s3w, s3b, outp);
}